// Round 10
// baseline (189.229 us; speedup 1.0000x reference)
//
#include <hip/hip_runtime.h>
#include <cfloat>

#define TOKENS 32768
#define DIM    320
#define NCODE  8192
#define APAD   40                 // ApackS row pitch in ushorts (80 B -> 8 bank-starts)
#define NTILE  64                 // tiles of 32 codes per wave (wave span = 2048)
#define CERT_UNITS 32u            // 32 * 7.63e-6 = 2.4e-4 dot-gap certification

typedef __attribute__((ext_vector_type(8)))  short short8;
typedef __attribute__((ext_vector_type(16))) float f32x16;
typedef unsigned short ushort_t;
typedef unsigned int   uint_t;

static __device__ __forceinline__ ushort_t f2bf(float f) {
    uint_t u = __float_as_uint(f);
    u += 0x7fffu + ((u >> 16) & 1u);
    return (ushort_t)(u >> 16);
}
static __device__ __forceinline__ float bf2f(ushort_t h) {
    return __uint_as_float(((uint_t)h) << 16);
}
static __device__ __forceinline__ uint_t pack2(ushort_t a, ushort_t b) {
    return (uint_t)a | ((uint_t)b << 16);
}
static __device__ __forceinline__ uint_t umaxu(uint_t a, uint_t b) { return a > b ? a : b; }
static __device__ __forceinline__ uint_t uminu(uint_t a, uint_t b) { return a < b ? a : b; }

// ---------------------------------------------------------------------------
// k0: codebook c2 (ascending-k fmaf, matches fallback math) + bf16 hi/lo pack.
// ---------------------------------------------------------------------------
__global__ __launch_bounds__(256) void pack_kernel(
    const float* __restrict__ cb,    // (8192, 16)
    float* __restrict__ c2o,         // (8192)
    ushort_t* __restrict__ cbpack)   // (8192, 32) [hi16|lo16]
{
    int j = blockIdx.x * 256 + threadIdx.x;
    const float4* cr4 = (const float4*)(cb + (size_t)j * 16);
    float4 c0 = cr4[0], c1 = cr4[1], c2v = cr4[2], c3 = cr4[3];
    float c[16] = {c0.x, c0.y, c0.z, c0.w, c1.x, c1.y, c1.z, c1.w,
                   c2v.x, c2v.y, c2v.z, c2v.w, c3.x, c3.y, c3.z, c3.w};
    float s = 0.f;
    #pragma unroll
    for (int k = 0; k < 16; ++k) s = fmaf(c[k], c[k], s);
    c2o[j] = s;
    ushort_t hi[16], lo[16];
    #pragma unroll
    for (int k = 0; k < 16; ++k) {
        hi[k] = f2bf(c[k]);
        lo[k] = f2bf(c[k] - bf2f(hi[k]));
    }
    uint4* dst = (uint4*)(cbpack + (size_t)j * 32);
    dst[0] = make_uint4(pack2(hi[0], hi[1]), pack2(hi[2], hi[3]),
                        pack2(hi[4], hi[5]), pack2(hi[6], hi[7]));
    dst[1] = make_uint4(pack2(hi[8], hi[9]), pack2(hi[10], hi[11]),
                        pack2(hi[12], hi[13]), pack2(hi[14], hi[15]));
    dst[2] = make_uint4(pack2(lo[0], lo[1]), pack2(lo[2], lo[3]),
                        pack2(lo[4], lo[5]), pack2(lo[6], lo[7]));
    dst[3] = make_uint4(pack2(lo[8], lo[9]), pack2(lo[10], lo[11]),
                        pack2(lo[12], lo[13]), pack2(lo[14], lo[15]));
}

// ---------------------------------------------------------------------------
// k1: fused projection + search + merge + cert + exact fallback.
// R7 shape (256 thr = 32 tokens x 4 waves, wave span 2048) but with NO LDS
// staging of P: P (20 KB) is read through L1 (hot after first touch; every
// block reads the same lines). LDS drops 31.2 KB -> ~6 KB, lifting the
// residency cap that held R7/R9 at ~2 blocks/CU (26% occupancy).
// ---------------------------------------------------------------------------
__global__ __launch_bounds__(256, 4) void fused_kernel(
    const float* __restrict__ x,        // (32768, 320)
    const float* __restrict__ P,        // (320, 16)
    const float* __restrict__ cb,       // (8192, 16) fp32
    const float* __restrict__ c2g,      // (8192)
    const ushort_t* __restrict__ cbpack,// (8192, 32)
    int* __restrict__ out)
{
    __shared__ ushort_t ApackS[32 * APAD];   // 2.5 KB padded rows
    __shared__ float tnS[32 * 16];           // 2 KB fp32 for fallback
    __shared__ float x2S[32];
    __shared__ uint_t mergeS[4][32][2];      // 1 KB
    __shared__ int flagS[36];                // [0..31] list, [32] count
    __shared__ float redE[4];
    __shared__ int   redI[4];

    int tid = threadIdx.x;
    if (tid == 0) flagS[32] = 0;

    // ---- Phase A: project 32 tokens (8 lanes/token), P via L1 ----
    int sub = tid & 7;
    int tk  = tid >> 3;                  // local token 0..31
    int tok = blockIdx.x * 32 + tk;
    {
        const float* xr = x + (size_t)tok * DIM;
        float acc[16];
        #pragma unroll
        for (int k = 0; k < 16; ++k) acc[k] = 0.f;
        for (int i = 0; i < 40; ++i) {
            int d = i * 8 + sub;
            float xv = xr[d];
            const float4* pr = (const float4*)(P + d * 16);
            float4 p0 = pr[0], p1 = pr[1], p2 = pr[2], p3 = pr[3];
            acc[0] = fmaf(xv, p0.x, acc[0]);   acc[1] = fmaf(xv, p0.y, acc[1]);
            acc[2] = fmaf(xv, p0.z, acc[2]);   acc[3] = fmaf(xv, p0.w, acc[3]);
            acc[4] = fmaf(xv, p1.x, acc[4]);   acc[5] = fmaf(xv, p1.y, acc[5]);
            acc[6] = fmaf(xv, p1.z, acc[6]);   acc[7] = fmaf(xv, p1.w, acc[7]);
            acc[8] = fmaf(xv, p2.x, acc[8]);   acc[9] = fmaf(xv, p2.y, acc[9]);
            acc[10] = fmaf(xv, p2.z, acc[10]); acc[11] = fmaf(xv, p2.w, acc[11]);
            acc[12] = fmaf(xv, p3.x, acc[12]); acc[13] = fmaf(xv, p3.y, acc[13]);
            acc[14] = fmaf(xv, p3.z, acc[14]); acc[15] = fmaf(xv, p3.w, acc[15]);
        }
        #pragma unroll
        for (int m = 1; m <= 4; m <<= 1) {
            #pragma unroll
            for (int k = 0; k < 16; ++k)
                acc[k] += __shfl_xor(acc[k], m);
        }
        float ss = 0.f;
        #pragma unroll
        for (int k = 0; k < 16; ++k) ss = fmaf(acc[k], acc[k], ss);
        float nrm = fmaxf(sqrtf(ss), 1e-12f);
        float inv = 1.0f / nrm;
        float t[16];
        #pragma unroll
        for (int k = 0; k < 16; ++k) t[k] = acc[k] * inv;
        float xx = 0.f;
        #pragma unroll
        for (int k = 0; k < 16; ++k) xx = fmaf(t[k], t[k], xx);

        ushort_t hi[16], lo[16];
        #pragma unroll
        for (int k = 0; k < 16; ++k) {
            hi[k] = f2bf(t[k]);
            lo[k] = f2bf(t[k] - bf2f(hi[k]));
        }
        if (sub < 4) {
            *(float4*)(tnS + tk * 16 + sub * 4) =
                make_float4(t[4 * sub], t[4 * sub + 1], t[4 * sub + 2], t[4 * sub + 3]);
        }
        uint4* dst = (uint4*)(ApackS + tk * APAD);   // 80 B rows, 16-B aligned
        if (sub == 4) dst[0] = make_uint4(pack2(hi[0], hi[1]), pack2(hi[2], hi[3]),
                                          pack2(hi[4], hi[5]), pack2(hi[6], hi[7]));
        if (sub == 5) dst[1] = make_uint4(pack2(hi[8], hi[9]), pack2(hi[10], hi[11]),
                                          pack2(hi[12], hi[13]), pack2(hi[14], hi[15]));
        if (sub == 6) dst[2] = make_uint4(pack2(lo[0], lo[1]), pack2(lo[2], lo[3]),
                                          pack2(lo[4], lo[5]), pack2(lo[6], lo[7]));
        if (sub == 7) dst[3] = make_uint4(pack2(lo[8], lo[9]), pack2(lo[10], lo[11]),
                                          pack2(lo[12], lo[13]), pack2(lo[14], lo[15]));
        if (sub == 0) x2S[tk] = xx;
    }
    __syncthreads();

    // ---- Phase B: per-wave search over its 2048-code span ----
    int lane = tid & 63;
    int wave = tid >> 6;
    int half = lane >> 5;
    int l31  = lane & 31;
    {
        short8 hiA = *(const short8*)(ApackS + l31 * APAD + half * 8);
        short8 loA = *(const short8*)(ApackS + l31 * APAD + 16 + half * 8);

        f32x16 zero = {};
        uint_t p1[16], p2[16];
        #pragma unroll
        for (int r = 0; r < 16; ++r) { p1[r] = 0u; p2[r] = 0u; }

        for (int t = 0; t < NTILE; ++t) {
            int crow = wave * (NTILE * 32) + t * 32 + l31;
            const ushort_t* cp = cbpack + (size_t)crow * 32;
            short8 hiB = *(const short8*)(cp + half * 8);
            short8 loB = *(const short8*)(cp + 16 + half * 8);

            f32x16 acc = __builtin_amdgcn_mfma_f32_32x32x16_bf16(hiA, hiB, zero, 0, 0, 0);
            acc = __builtin_amdgcn_mfma_f32_32x32x16_bf16(loA, hiB, acc, 0, 0, 0);
            acc = __builtin_amdgcn_mfma_f32_32x32x16_bf16(hiA, loB, acc, 0, 0, 0);

            uint_t inv = 8191u - (uint_t)crow;
            #pragma unroll
            for (int r = 0; r < 16; ++r) {
                float kf = fmaf(acc[r], 131072.0f, 131072.0f);
                uint_t ku = (uint_t)kf;       // v_cvt_u32_f32: trunc, neg->0
                uint_t p  = (ku << 13) | inv;
                p2[r] = umaxu(p2[r], uminu(p, p1[r]));
                p1[r] = umaxu(p1[r], p);
            }
        }
        #pragma unroll
        for (int mask = 1; mask <= 16; mask <<= 1) {
            #pragma unroll
            for (int r = 0; r < 16; ++r) {
                uint_t a1 = (uint_t)__shfl_xor((int)p1[r], mask);
                uint_t a2 = (uint_t)__shfl_xor((int)p2[r], mask);
                uint_t np2 = umaxu(uminu(p1[r], a1), umaxu(p2[r], a2));
                p1[r] = umaxu(p1[r], a1);
                p2[r] = np2;
            }
        }
        #pragma unroll
        for (int r = 0; r < 16; ++r) {
            if (l31 == r) {
                int mrow = (r & 3) + 8 * (r >> 2) + 4 * half;
                mergeS[wave][mrow][0] = p1[r];
                mergeS[wave][mrow][1] = p2[r];
            }
        }
    }
    __syncthreads();

    // ---- Phase C: merge 4 waves, decode, certify ----
    if (tid < 32) {
        uint_t p1 = mergeS[0][tid][0], p2 = mergeS[0][tid][1];
        #pragma unroll
        for (int w = 1; w < 4; ++w) {
            uint_t a1 = mergeS[w][tid][0];
            uint_t a2 = mergeS[w][tid][1];
            uint_t np2 = umaxu(uminu(p1, a1), umaxu(p2, a2));
            p1 = umaxu(p1, a1);
            p2 = np2;
        }
        if ((p1 >> 13) - (p2 >> 13) <= CERT_UNITS) {
            int pz = atomicAdd(&flagS[32], 1);
            flagS[pz] = tid;
        } else {
            out[blockIdx.x * 32 + tid] = 8191 - (int)(p1 & 8191u);
        }
    }
    __syncthreads();

    // ---- Phase D: exact fp32 rescan of flagged tokens (rare) ----
    // R1-validated rounding: ascending fmaf dot, fmaf(-2,dot,x2+c2),
    // lexicographic (e, j) min == first-occurrence argmin.
    int nf = flagS[32];
    for (int fi = 0; fi < nf; ++fi) {
        int ftk = flagS[fi];
        float a[16];
        #pragma unroll
        for (int k = 0; k < 16; ++k) a[k] = tnS[ftk * 16 + k];
        float xx = x2S[ftk];
        float mn = FLT_MAX;
        int   id = 0x7fffffff;
        for (int c = 0; c < 32; ++c) {
            int j = c * 256 + tid;
            const float4* c4 = (const float4*)(cb + (size_t)j * 16);
            float4 c0 = c4[0], c1 = c4[1], c2v = c4[2], c3 = c4[3];
            float dot = 0.f;
            dot = fmaf(a[0], c0.x, dot);   dot = fmaf(a[1], c0.y, dot);
            dot = fmaf(a[2], c0.z, dot);   dot = fmaf(a[3], c0.w, dot);
            dot = fmaf(a[4], c1.x, dot);   dot = fmaf(a[5], c1.y, dot);
            dot = fmaf(a[6], c1.z, dot);   dot = fmaf(a[7], c1.w, dot);
            dot = fmaf(a[8], c2v.x, dot);  dot = fmaf(a[9], c2v.y, dot);
            dot = fmaf(a[10], c2v.z, dot); dot = fmaf(a[11], c2v.w, dot);
            dot = fmaf(a[12], c3.x, dot);  dot = fmaf(a[13], c3.y, dot);
            dot = fmaf(a[14], c3.z, dot);  dot = fmaf(a[15], c3.w, dot);
            float e = fmaf(-2.f, dot, xx + c2g[j]);
            if (e < mn || (e == mn && j < id)) { mn = e; id = j; }
        }
        #pragma unroll
        for (int mask = 1; mask <= 32; mask <<= 1) {
            float pmn = __shfl_xor(mn, mask);
            int   pid = __shfl_xor(id, mask);
            if (pmn < mn || (pmn == mn && pid < id)) { mn = pmn; id = pid; }
        }
        if (lane == 0) { redE[wave] = mn; redI[wave] = id; }
        __syncthreads();
        if (tid == 0) {
            #pragma unroll
            for (int w = 1; w < 4; ++w) {
                float pe = redE[w]; int pi = redI[w];
                if (pe < mn || (pe == mn && pi < id)) { mn = pe; id = pi; }
            }
            out[blockIdx.x * 32 + ftk] = id;
        }
        __syncthreads();
    }
}

extern "C" void kernel_launch(void* const* d_in, const int* in_sizes, int n_in,
                              void* d_out, int out_size, void* d_ws, size_t ws_size,
                              hipStream_t stream) {
    const float* x   = (const float*)d_in[0];
    const float* P   = (const float*)d_in[1];
    const float* cbn = (const float*)d_in[2];

    float*    c2     = (float*)d_ws;                      // 8192 f
    ushort_t* cbpack = (ushort_t*)(c2 + NCODE);           // 8192*32 ushorts
    int* labels = (int*)d_out;

    pack_kernel<<<NCODE / 256, 256, 0, stream>>>(cbn, c2, cbpack);
    fused_kernel<<<TOKENS / 32, 256, 0, stream>>>(x, P, cbn, c2, cbpack, labels);
}

// Round 11
// 161.310 us; speedup vs baseline: 1.1731x; 1.1731x over previous
//
#include <hip/hip_runtime.h>
#include <cfloat>

#define TOKENS 32768
#define DIM    320
#define NCODE  8192
#define PROW   20                 // P row pitch in LDS floats (stride-8 conflict-free)
#define APAD   40                 // ApackS row pitch in ushorts (80 B -> 8 bank-starts)
#define NTILE  64                 // tiles of 32 codes per wave (wave span = 2048)
#define CERT_UNITS 32u            // 32 * 7.63e-6 = 2.4e-4 dot-gap certification

typedef __attribute__((ext_vector_type(8)))  short short8;
typedef __attribute__((ext_vector_type(16))) float f32x16;
typedef unsigned short ushort_t;
typedef unsigned int   uint_t;

static __device__ __forceinline__ ushort_t f2bf(float f) {
    uint_t u = __float_as_uint(f);
    u += 0x7fffu + ((u >> 16) & 1u);
    return (ushort_t)(u >> 16);
}
static __device__ __forceinline__ float bf2f(ushort_t h) {
    return __uint_as_float(((uint_t)h) << 16);
}
static __device__ __forceinline__ uint_t pack2(ushort_t a, ushort_t b) {
    return (uint_t)a | ((uint_t)b << 16);
}
static __device__ __forceinline__ uint_t umaxu(uint_t a, uint_t b) { return a > b ? a : b; }
static __device__ __forceinline__ uint_t uminu(uint_t a, uint_t b) { return a < b ? a : b; }

// ---------------------------------------------------------------------------
// k0: codebook c2 (ascending-k fmaf, matches fallback math) + bf16 hi/lo pack.
// ---------------------------------------------------------------------------
__global__ __launch_bounds__(256) void pack_kernel(
    const float* __restrict__ cb,    // (8192, 16)
    float* __restrict__ c2o,         // (8192)
    ushort_t* __restrict__ cbpack)   // (8192, 32) [hi16|lo16]
{
    int j = blockIdx.x * 256 + threadIdx.x;
    const float4* cr4 = (const float4*)(cb + (size_t)j * 16);
    float4 c0 = cr4[0], c1 = cr4[1], c2v = cr4[2], c3 = cr4[3];
    float c[16] = {c0.x, c0.y, c0.z, c0.w, c1.x, c1.y, c1.z, c1.w,
                   c2v.x, c2v.y, c2v.z, c2v.w, c3.x, c3.y, c3.z, c3.w};
    float s = 0.f;
    #pragma unroll
    for (int k = 0; k < 16; ++k) s = fmaf(c[k], c[k], s);
    c2o[j] = s;
    ushort_t hi[16], lo[16];
    #pragma unroll
    for (int k = 0; k < 16; ++k) {
        hi[k] = f2bf(c[k]);
        lo[k] = f2bf(c[k] - bf2f(hi[k]));
    }
    uint4* dst = (uint4*)(cbpack + (size_t)j * 32);
    dst[0] = make_uint4(pack2(hi[0], hi[1]), pack2(hi[2], hi[3]),
                        pack2(hi[4], hi[5]), pack2(hi[6], hi[7]));
    dst[1] = make_uint4(pack2(hi[8], hi[9]), pack2(hi[10], hi[11]),
                        pack2(hi[12], hi[13]), pack2(hi[14], hi[15]));
    dst[2] = make_uint4(pack2(lo[0], lo[1]), pack2(lo[2], lo[3]),
                        pack2(lo[4], lo[5]), pack2(lo[6], lo[7]));
    dst[3] = make_uint4(pack2(lo[8], lo[9]), pack2(lo[10], lo[11]),
                        pack2(lo[12], lo[13]), pack2(lo[14], lo[15]));
}

// ---------------------------------------------------------------------------
// k1: fused projection + search + merge + cert + exact fallback.
// R9 structure (256 thr = 32 tokens x 4 waves, span 2048, Ps in LDS) with a
// software-pipelined Phase B: per iteration, issue B-loads(t), then run the
// epilogue of tile t-1 (covers both the B-load latency and the in-flight
// MFMA chain), then issue MFMAs(t). launch_bounds (256,2) widens the VGPR
// cap to 256 so the accumulators can live in ArchVGPRs (at 128-cap the
// compiler split to AGPRs -> per-tile v_accvgpr_read tax).
// ---------------------------------------------------------------------------
__global__ __launch_bounds__(256, 2) void fused_kernel(
    const float* __restrict__ x,        // (32768, 320)
    const float* __restrict__ P,        // (320, 16)
    const float* __restrict__ cb,       // (8192, 16) fp32
    const float* __restrict__ c2g,      // (8192)
    const ushort_t* __restrict__ cbpack,// (8192, 32)
    int* __restrict__ out)
{
    __shared__ float Ps[DIM * PROW];         // 25.6 KB
    __shared__ ushort_t ApackS[32 * APAD];   // 2.5 KB padded rows
    __shared__ float tnS[32 * 16];           // 2 KB fp32 for fallback
    __shared__ float x2S[32];
    __shared__ uint_t mergeS[4][32][2];      // 1 KB
    __shared__ int flagS[36];                // [0..31] list, [32] count
    __shared__ float redE[4];
    __shared__ int   redI[4];

    int tid = threadIdx.x;
    if (tid == 0) flagS[32] = 0;

    // ---- Phase A: stage P, project 32 tokens (8 lanes/token) ----
    {
        const float4* P4 = (const float4*)P;
        #pragma unroll
        for (int i = 0; i < 5; ++i) {
            int idx = tid + i * 256;
            int row = idx >> 2, col = idx & 3;
            *(float4*)(Ps + row * PROW + col * 4) = P4[idx];
        }
    }
    __syncthreads();

    int sub = tid & 7;
    int tk  = tid >> 3;                  // local token 0..31
    int tok = blockIdx.x * 32 + tk;
    {
        const float* xr = x + (size_t)tok * DIM;
        float acc[16];
        #pragma unroll
        for (int k = 0; k < 16; ++k) acc[k] = 0.f;
        for (int i = 0; i < 40; ++i) {
            int d = i * 8 + sub;
            float xv = xr[d];
            const float4* pr = (const float4*)(Ps + d * PROW);
            float4 p0 = pr[0], p1 = pr[1], p2 = pr[2], p3 = pr[3];
            acc[0] = fmaf(xv, p0.x, acc[0]);   acc[1] = fmaf(xv, p0.y, acc[1]);
            acc[2] = fmaf(xv, p0.z, acc[2]);   acc[3] = fmaf(xv, p0.w, acc[3]);
            acc[4] = fmaf(xv, p1.x, acc[4]);   acc[5] = fmaf(xv, p1.y, acc[5]);
            acc[6] = fmaf(xv, p1.z, acc[6]);   acc[7] = fmaf(xv, p1.w, acc[7]);
            acc[8] = fmaf(xv, p2.x, acc[8]);   acc[9] = fmaf(xv, p2.y, acc[9]);
            acc[10] = fmaf(xv, p2.z, acc[10]); acc[11] = fmaf(xv, p2.w, acc[11]);
            acc[12] = fmaf(xv, p3.x, acc[12]); acc[13] = fmaf(xv, p3.y, acc[13]);
            acc[14] = fmaf(xv, p3.z, acc[14]); acc[15] = fmaf(xv, p3.w, acc[15]);
        }
        #pragma unroll
        for (int m = 1; m <= 4; m <<= 1) {
            #pragma unroll
            for (int k = 0; k < 16; ++k)
                acc[k] += __shfl_xor(acc[k], m);
        }
        float ss = 0.f;
        #pragma unroll
        for (int k = 0; k < 16; ++k) ss = fmaf(acc[k], acc[k], ss);
        float nrm = fmaxf(sqrtf(ss), 1e-12f);
        float inv = 1.0f / nrm;
        float t[16];
        #pragma unroll
        for (int k = 0; k < 16; ++k) t[k] = acc[k] * inv;
        float xx = 0.f;
        #pragma unroll
        for (int k = 0; k < 16; ++k) xx = fmaf(t[k], t[k], xx);

        ushort_t hi[16], lo[16];
        #pragma unroll
        for (int k = 0; k < 16; ++k) {
            hi[k] = f2bf(t[k]);
            lo[k] = f2bf(t[k] - bf2f(hi[k]));
        }
        if (sub < 4) {
            *(float4*)(tnS + tk * 16 + sub * 4) =
                make_float4(t[4 * sub], t[4 * sub + 1], t[4 * sub + 2], t[4 * sub + 3]);
        }
        uint4* dst = (uint4*)(ApackS + tk * APAD);   // 80 B rows, 16-B aligned
        if (sub == 4) dst[0] = make_uint4(pack2(hi[0], hi[1]), pack2(hi[2], hi[3]),
                                          pack2(hi[4], hi[5]), pack2(hi[6], hi[7]));
        if (sub == 5) dst[1] = make_uint4(pack2(hi[8], hi[9]), pack2(hi[10], hi[11]),
                                          pack2(hi[12], hi[13]), pack2(hi[14], hi[15]));
        if (sub == 6) dst[2] = make_uint4(pack2(lo[0], lo[1]), pack2(lo[2], lo[3]),
                                          pack2(lo[4], lo[5]), pack2(lo[6], lo[7]));
        if (sub == 7) dst[3] = make_uint4(pack2(lo[8], lo[9]), pack2(lo[10], lo[11]),
                                          pack2(lo[12], lo[13]), pack2(lo[14], lo[15]));
        if (sub == 0) x2S[tk] = xx;
    }
    __syncthreads();

    // ---- Phase B: software-pipelined search over this wave's 2048 codes ----
    int lane = tid & 63;
    int wave = tid >> 6;
    int half = lane >> 5;
    int l31  = lane & 31;
    {
        short8 hiA = *(const short8*)(ApackS + l31 * APAD + half * 8);
        short8 loA = *(const short8*)(ApackS + l31 * APAD + 16 + half * 8);

        f32x16 zero = {};
        uint_t p1[16], p2[16];
        #pragma unroll
        for (int r = 0; r < 16; ++r) { p1[r] = 0u; p2[r] = 0u; }

        int base = wave * (NTILE * 32) + l31;

        // prologue: tile 0 loads + MFMAs
        const ushort_t* cp0 = cbpack + (size_t)base * 32;
        short8 hiB0 = *(const short8*)(cp0 + half * 8);
        short8 loB0 = *(const short8*)(cp0 + 16 + half * 8);
        f32x16 accP = __builtin_amdgcn_mfma_f32_32x32x16_bf16(hiA, hiB0, zero, 0, 0, 0);
        accP = __builtin_amdgcn_mfma_f32_32x32x16_bf16(loA, hiB0, accP, 0, 0, 0);
        accP = __builtin_amdgcn_mfma_f32_32x32x16_bf16(hiA, loB0, accP, 0, 0, 0);
        uint_t invP = 8191u - (uint_t)base;

        #pragma unroll 2
        for (int t = 1; t < NTILE; ++t) {
            int crow = base + t * 32;
            // 1) issue B-loads for tile t (no dependent use yet)
            const ushort_t* cp = cbpack + (size_t)crow * 32;
            short8 hiB = *(const short8*)(cp + half * 8);
            short8 loB = *(const short8*)(cp + 16 + half * 8);

            // 2) epilogue of tile t-1 — covers B-load latency + prior MFMA chain
            #pragma unroll
            for (int r = 0; r < 16; ++r) {
                float kf = fmaf(accP[r], 131072.0f, 131072.0f);
                uint_t ku = (uint_t)kf;       // v_cvt_u32_f32: trunc, neg->0
                uint_t p  = (ku << 13) | invP;
                p2[r] = umaxu(p2[r], uminu(p, p1[r]));
                p1[r] = umaxu(p1[r], p);
            }

            // 3) issue MFMAs for tile t (result consumed next iteration)
            f32x16 acc = __builtin_amdgcn_mfma_f32_32x32x16_bf16(hiA, hiB, zero, 0, 0, 0);
            acc = __builtin_amdgcn_mfma_f32_32x32x16_bf16(loA, hiB, acc, 0, 0, 0);
            acc = __builtin_amdgcn_mfma_f32_32x32x16_bf16(hiA, loB, acc, 0, 0, 0);
            accP = acc;
            invP = 8191u - (uint_t)crow;
        }
        // drain: epilogue of the last tile
        #pragma unroll
        for (int r = 0; r < 16; ++r) {
            float kf = fmaf(accP[r], 131072.0f, 131072.0f);
            uint_t ku = (uint_t)kf;
            uint_t p  = (ku << 13) | invP;
            p2[r] = umaxu(p2[r], uminu(p, p1[r]));
            p1[r] = umaxu(p1[r], p);
        }

        #pragma unroll
        for (int mask = 1; mask <= 16; mask <<= 1) {
            #pragma unroll
            for (int r = 0; r < 16; ++r) {
                uint_t a1 = (uint_t)__shfl_xor((int)p1[r], mask);
                uint_t a2 = (uint_t)__shfl_xor((int)p2[r], mask);
                uint_t np2 = umaxu(uminu(p1[r], a1), umaxu(p2[r], a2));
                p1[r] = umaxu(p1[r], a1);
                p2[r] = np2;
            }
        }
        #pragma unroll
        for (int r = 0; r < 16; ++r) {
            if (l31 == r) {
                int mrow = (r & 3) + 8 * (r >> 2) + 4 * half;
                mergeS[wave][mrow][0] = p1[r];
                mergeS[wave][mrow][1] = p2[r];
            }
        }
    }
    __syncthreads();

    // ---- Phase C: merge 4 waves, decode, certify ----
    if (tid < 32) {
        uint_t p1 = mergeS[0][tid][0], p2 = mergeS[0][tid][1];
        #pragma unroll
        for (int w = 1; w < 4; ++w) {
            uint_t a1 = mergeS[w][tid][0];
            uint_t a2 = mergeS[w][tid][1];
            uint_t np2 = umaxu(uminu(p1, a1), umaxu(p2, a2));
            p1 = umaxu(p1, a1);
            p2 = np2;
        }
        if ((p1 >> 13) - (p2 >> 13) <= CERT_UNITS) {
            int pz = atomicAdd(&flagS[32], 1);
            flagS[pz] = tid;
        } else {
            out[blockIdx.x * 32 + tid] = 8191 - (int)(p1 & 8191u);
        }
    }
    __syncthreads();

    // ---- Phase D: exact fp32 rescan of flagged tokens (rare) ----
    // R1-validated rounding: ascending fmaf dot, fmaf(-2,dot,x2+c2),
    // lexicographic (e, j) min == first-occurrence argmin.
    int nf = flagS[32];
    for (int fi = 0; fi < nf; ++fi) {
        int ftk = flagS[fi];
        float a[16];
        #pragma unroll
        for (int k = 0; k < 16; ++k) a[k] = tnS[ftk * 16 + k];
        float xx = x2S[ftk];
        float mn = FLT_MAX;
        int   id = 0x7fffffff;
        for (int c = 0; c < 32; ++c) {
            int j = c * 256 + tid;
            const float4* c4 = (const float4*)(cb + (size_t)j * 16);
            float4 c0 = c4[0], c1 = c4[1], c2v = c4[2], c3 = c4[3];
            float dot = 0.f;
            dot = fmaf(a[0], c0.x, dot);   dot = fmaf(a[1], c0.y, dot);
            dot = fmaf(a[2], c0.z, dot);   dot = fmaf(a[3], c0.w, dot);
            dot = fmaf(a[4], c1.x, dot);   dot = fmaf(a[5], c1.y, dot);
            dot = fmaf(a[6], c1.z, dot);   dot = fmaf(a[7], c1.w, dot);
            dot = fmaf(a[8], c2v.x, dot);  dot = fmaf(a[9], c2v.y, dot);
            dot = fmaf(a[10], c2v.z, dot); dot = fmaf(a[11], c2v.w, dot);
            dot = fmaf(a[12], c3.x, dot);  dot = fmaf(a[13], c3.y, dot);
            dot = fmaf(a[14], c3.z, dot);  dot = fmaf(a[15], c3.w, dot);
            float e = fmaf(-2.f, dot, xx + c2g[j]);
            if (e < mn || (e == mn && j < id)) { mn = e; id = j; }
        }
        #pragma unroll
        for (int mask = 1; mask <= 32; mask <<= 1) {
            float pmn = __shfl_xor(mn, mask);
            int   pid = __shfl_xor(id, mask);
            if (pmn < mn || (pmn == mn && pid < id)) { mn = pmn; id = pid; }
        }
        if (lane == 0) { redE[wave] = mn; redI[wave] = id; }
        __syncthreads();
        if (tid == 0) {
            #pragma unroll
            for (int w = 1; w < 4; ++w) {
                float pe = redE[w]; int pi = redI[w];
                if (pe < mn || (pe == mn && pi < id)) { mn = pe; id = pi; }
            }
            out[blockIdx.x * 32 + ftk] = id;
        }
        __syncthreads();
    }
}

extern "C" void kernel_launch(void* const* d_in, const int* in_sizes, int n_in,
                              void* d_out, int out_size, void* d_ws, size_t ws_size,
                              hipStream_t stream) {
    const float* x   = (const float*)d_in[0];
    const float* P   = (const float*)d_in[1];
    const float* cbn = (const float*)d_in[2];

    float*    c2     = (float*)d_ws;                      // 8192 f
    ushort_t* cbpack = (ushort_t*)(c2 + NCODE);           // 8192*32 ushorts
    int* labels = (int*)d_out;

    pack_kernel<<<NCODE / 256, 256, 0, stream>>>(cbn, c2, cbpack);
    fused_kernel<<<TOKENS / 32, 256, 0, stream>>>(x, P, cbn, c2, cbpack, labels);
}